// Round 10
// baseline (122.920 us; speedup 1.0000x reference)
//
#include <hip/hip_runtime.h>

#define D 1024
#define NB 8
#define T 4096

typedef float fvec4 __attribute__((ext_vector_type(4)));

// ---------------- leaves: partial sums over t-chunks of 32 ----------------
// lpart[b][leaf][tc][col] = sum of 32 rows (rows 0..2047 of each batch)
__global__ void __launch_bounds__(256, 2) leaves_partial(const float* __restrict__ x,
                                                         float* __restrict__ lpart) {
    int bid = blockIdx.x;                  // 512 blocks
    int b = bid >> 6, leaf = (bid >> 3) & 7, tc = bid & 7;
    int tid = threadIdx.x;
    const fvec4* xp = (const fvec4*)x;
    size_t base = ((size_t)(b * T + leaf * 256 + tc * 32)) * 256 + tid;
    fvec4 acc = {0.f, 0.f, 0.f, 0.f};
#pragma unroll 8
    for (int tt = 0; tt < 32; ++tt)
        acc += xp[base + (size_t)tt * 256];
    ((fvec4*)lpart)[(size_t)((b * 8 + leaf) * 8 + tc) * 256 + tid] = acc;
}

// ---------------- fused tree-level GEMM (float4 W loads) ------------------
// block (node,kc): gout[node][kc][b][col] partials, 4 cols/thread, unroll 4.
// MODE 0: stage = mean of 8 lpart partials.
// MODE 1: stage = gate(reduce KCPREV prev partials); cooperative split when
//         VALS < 256 so every thread reduces <=64 elements.
template <int KCH, int NKC, int KCPREV, int MODE>
__global__ void __launch_bounds__(256, 2) tree_gemm(const float* __restrict__ gprev,
                                                    const float* __restrict__ W,
                                                    const float* __restrict__ bias,
                                                    const float* __restrict__ bt,
                                                    float* __restrict__ gout,
                                                    int node_base, int prev_base) {
    int bid = blockIdx.x;
    int node = bid / NKC;
    int kc = bid % NKC;
    int k0 = kc * KCH;
    int tid = threadIdx.x;

    __shared__ float fs[KCH * 8];
    __shared__ float red[256];

    if (MODE == 0) {
        for (int idx = tid; idx < KCH * 8; idx += 256) {
            int kk = idx % KCH;
            int b = idx / KCH;
            int col = (k0 + kk) & 1023;
            float p = 0.f;
#pragma unroll
            for (int tc = 0; tc < 8; ++tc)
                p += gprev[(size_t)((b * 8 + node) * 8 + tc) * D + col];
            fs[kk * 8 + b] = p * (1.0f / 256.0f);
        }
    } else {
        constexpr int VALS = KCH * 8;
        constexpr int SPL = (VALS >= 256) ? 1 : (256 / VALS);
        constexpr int PER = KCPREV / SPL;
        if (SPL == 1) {
            for (int idx = tid; idx < VALS; idx += 256) {
                int kk = idx % KCH;
                int b = idx / KCH;
                int k = k0 + kk;
                int col = k & 1023;
                int src = 2 * node + (k >> 10);
                float p = bias[(size_t)(prev_base + src) * D + col];
#pragma unroll 16
                for (int kcp = 0; kcp < KCPREV; ++kcp)
                    p += gprev[(size_t)((src * KCPREV + kcp) * 8 + b) * D + col];
                float u = p - bt[(size_t)(prev_base + src) * D + col];
                fs[kk * 8 + b] = (u > 0.0f) ? p : 0.0f;
            }
        } else {
            // 256 = VALS*SPL threads: value v = tid%VALS, slice = tid/VALS
            int v = tid % VALS;
            int part = tid / VALS;
            int kk = v % KCH;
            int b = v / KCH;
            int k = k0 + kk;
            int col = k & 1023;
            int src = 2 * node + (k >> 10);
            float p = 0.f;
#pragma unroll 8
            for (int kcp = part * PER; kcp < (part + 1) * PER; ++kcp)
                p += gprev[(size_t)((src * KCPREV + kcp) * 8 + b) * D + col];
            red[part * VALS + v] = p;
            __syncthreads();
            if (tid < VALS) {
                float tot = bias[(size_t)(prev_base + src) * D + col];
#pragma unroll
                for (int s = 0; s < SPL; ++s) tot += red[s * VALS + v];
                float u = tot - bt[(size_t)(prev_base + src) * D + col];
                fs[kk * 8 + b] = (u > 0.0f) ? tot : 0.0f;
            }
        }
    }
    __syncthreads();

    const fvec4* Wp = (const fvec4*)W +
                      ((size_t)(node_base + node) * 2048 + (size_t)k0) * 256 + tid;
    fvec4 acc[8];
#pragma unroll
    for (int b = 0; b < 8; ++b) acc[b] = (fvec4){0.f, 0.f, 0.f, 0.f};
#pragma unroll 4
    for (int kk = 0; kk < KCH; ++kk) {
        fvec4 w = __builtin_nontemporal_load(Wp + (size_t)kk * 256);
#pragma unroll
        for (int b = 0; b < 8; ++b) acc[b] += w * fs[kk * 8 + b];
    }
    fvec4* op = (fvec4*)gout + (size_t)((node * NKC + kc) * 8) * 256 + tid;
#pragma unroll
    for (int b = 0; b < 8; ++b) op[(size_t)b * 256] = acc[b];
}

// ---------------- root: reduce level-0 partials, bias, gate ---------------
// gpart = [KC kc][8 b][1024 col]; 512 blocks: (b, 16-col group)
template <int KC>
__global__ void __launch_bounds__(256, 2) root_gate(const float* __restrict__ gpart,
                                                    const float* __restrict__ bias,
                                                    const float* __restrict__ bt,
                                                    float* __restrict__ root) {
    int b = blockIdx.x >> 6;
    int colg = blockIdx.x & 63;
    int tid = threadIdx.x;
    int c = tid & 15, s = tid >> 4;
    int col = colg * 16 + c;
    float p = 0.f;
#pragma unroll 4
    for (int kc = s; kc < KC; kc += 16)
        p += gpart[(size_t)(kc * 8 + b) * D + col];
    __shared__ float sm[256];
    sm[s * 16 + c] = p;
    __syncthreads();
    if (tid < 16) {
        int col2 = colg * 16 + tid;
        float tot = bias[col2];
#pragma unroll
        for (int ss = 0; ss < 16; ++ss) tot += sm[ss * 16 + tid];
        float u = tot - bt[col2];
        root[b * D + col2] = (u > 0.0f) ? tot : 0.0f;
    }
}

// ---------------- final: out = layernorm(root[b] + x[row]) ----------------
// 4096 blocks x 8 rows; one wave per row-pair; x cached, out NT-stored.
__global__ void __launch_bounds__(256, 2) add_ln(const float* __restrict__ x,
                                                 const float* __restrict__ root,
                                                 const float* __restrict__ lw,
                                                 const float* __restrict__ lb,
                                                 float* __restrict__ out) {
    int tid = threadIdx.x;
    int wv = tid >> 6, lane = tid & 63;
    int row0 = blockIdx.x * 8 + wv;
    int b = (blockIdx.x * 8) >> 12;
    const fvec4* xp = (const fvec4*)x;
    const fvec4* rp = (const fvec4*)root + b * 256;
    const fvec4* lwp = (const fvec4*)lw;
    const fvec4* lbp = (const fvec4*)lb;

    fvec4 rv[4], lwv[4], lbv[4];
#pragma unroll
    for (int j = 0; j < 4; ++j) {
        rv[j] = rp[j * 64 + lane];
        lwv[j] = lwp[j * 64 + lane];
        lbv[j] = lbp[j * 64 + lane];
    }
#pragma unroll
    for (int r = 0; r < 2; ++r) {
        int row = row0 + r * 4;
        fvec4 v[4];
        float s = 0.f, q = 0.f;
#pragma unroll
        for (int j = 0; j < 4; ++j) {
            fvec4 xv = xp[(size_t)row * 256 + j * 64 + lane];
            v[j] = xv + rv[j];
            s += v[j].x + v[j].y + v[j].z + v[j].w;
            q += v[j].x * v[j].x + v[j].y * v[j].y + v[j].z * v[j].z + v[j].w * v[j].w;
        }
#pragma unroll
        for (int off = 32; off; off >>= 1) {
            s += __shfl_xor(s, off);
            q += __shfl_xor(q, off);
        }
        float mean = s * (1.0f / D);
        float var = q * (1.0f / D) - mean * mean;
        float rstd = rsqrtf(var + 1e-5f);
        fvec4* op = (fvec4*)out + (size_t)row * 256;
#pragma unroll
        for (int j = 0; j < 4; ++j) {
            fvec4 o = (v[j] - mean) * rstd * lwv[j] + lbv[j];
            __builtin_nontemporal_store(o, op + j * 64 + lane);
        }
    }
}

// ===================== launcher =====================

extern "C" void kernel_launch(void* const* d_in, const int* in_sizes, int n_in,
                              void* d_out, int out_size, void* d_ws, size_t ws_size,
                              hipStream_t stream) {
    const float* x    = (const float*)d_in[0];
    const float* W    = (const float*)d_in[1];
    const float* bias = (const float*)d_in[2];
    const float* bt   = (const float*)d_in[3];
    const float* lw   = (const float*)d_in[4];
    const float* lb   = (const float*)d_in[5];
    float* out = (float*)d_out;

    float* ws = (float*)d_ws;

    // New geometry needs: lpart 512K | gA 4M | gB 4M | root 8K floats = 35.7 MB
    const size_t NEED = (size_t)(524288 + 4194304 + 4194304 + 8192) * 4;

    leaves_partial<<<512, 256, 0, stream>>>(x, ws /*lpart at base*/);

    if (ws_size >= NEED) {
        float* lpart = ws;
        float* gA    = lpart + 524288;   // holds leaf out (16 MB) then L1 out (16 MB)
        float* gB    = gA + 4194304;     // holds L2 out (16 MB) then L0 out (8 MB)
        float* root  = gB + 4194304;

        // leaf (nodes 7..14): mean(lpart) -> gA   [8 x 64 kc, KCH=32, 512 blk]
        tree_gemm<32, 64, 8, 0><<<512, 256, 0, stream>>>(lpart, W, bias, bt, gA, 7, 0);
        // level 2 (3..6): gate(gA, base 7) -> gB  [4 x 128 kc, KCH=16, 512 blk]
        tree_gemm<16, 128, 64, 1><<<512, 256, 0, stream>>>(gA, W, bias, bt, gB, 3, 7);
        // level 1 (1..2): gate(gB, base 3) -> gA  [2 x 256 kc, KCH=8, 512 blk]
        tree_gemm<8, 256, 128, 1><<<512, 256, 0, stream>>>(gB, W, bias, bt, gA, 1, 3);
        // level 0 (0): gate(gA, base 1) -> gB     [1 x 256 kc, KCH=8, 256 blk]
        tree_gemm<8, 256, 256, 1><<<256, 256, 0, stream>>>(gA, W, bias, bt, gB, 0, 1);
        // root = gate(bias0 + sum_kc gB, bt0)
        root_gate<256><<<512, 256, 0, stream>>>(gB, bias, bt, root);
        add_ln<<<NB * T / 8, 256, 0, stream>>>(x, root, lw, lb, out);
    } else {
        // fallback: R9 geometry (~19 MB)
        float* lpart = ws;
        float* gA    = lpart + 524288;
        float* gB    = gA + 2097152;
        float* root  = gB + 2097152;

        tree_gemm<64, 32, 8, 0><<<256, 256, 0, stream>>>(lpart, W, bias, bt, gA, 7, 0);
        tree_gemm<32, 64, 32, 1><<<256, 256, 0, stream>>>(gA, W, bias, bt, gB, 3, 7);
        tree_gemm<16, 128, 64, 1><<<256, 256, 0, stream>>>(gB, W, bias, bt, gA, 1, 3);
        tree_gemm<8, 256, 128, 1><<<256, 256, 0, stream>>>(gA, W, bias, bt, gB, 0, 1);
        root_gate<256><<<512, 256, 0, stream>>>(gB, bias, bt, root);
        add_ln<<<NB * T / 8, 256, 0, stream>>>(x, root, lw, lb, out);
    }
}

// Round 11
// 105.906 us; speedup vs baseline: 1.1606x; 1.1606x over previous
//
#include <hip/hip_runtime.h>

#define D 1024
#define NB 8
#define T 4096

typedef float fvec4 __attribute__((ext_vector_type(4)));

// ---------------- leaves: partial sums over t-chunks of 32 ----------------
// lpart[b][leaf][tc][col] = sum of 32 rows (rows 0..2047 of each batch)
__global__ void __launch_bounds__(256, 2) leaves_partial(const float* __restrict__ x,
                                                         float* __restrict__ lpart) {
    int bid = blockIdx.x;                  // 512 blocks
    int b = bid >> 6, leaf = (bid >> 3) & 7, tc = bid & 7;
    int tid = threadIdx.x;
    const fvec4* xp = (const fvec4*)x;
    size_t base = ((size_t)(b * T + leaf * 256 + tc * 32)) * 256 + tid;
    fvec4 acc = {0.f, 0.f, 0.f, 0.f};
#pragma unroll 8
    for (int tt = 0; tt < 32; ++tt)
        acc += xp[base + (size_t)tt * 256];
    ((fvec4*)lpart)[(size_t)((b * 8 + leaf) * 8 + tc) * 256 + tid] = acc;
}

// ---------------- fused tree-level GEMM (float4 W loads) ------------------
// block (node,kc): gout[node][kc][b][col] partials, 4 cols/thread.
// MODE 0: stage = mean of 8 lpart partials. MODE 1: stage = gate(reduce prev).
// W prefetch: first 4 W-vectors loaded BEFORE staging (compiler cannot hoist
// loads across __syncthreads); main loop software-pipelined 4 deep.
template <int KCH, int NKC, int KCPREV, int MODE>
__global__ void __launch_bounds__(256, 2) tree_gemm(const float* __restrict__ gprev,
                                                    const float* __restrict__ W,
                                                    const float* __restrict__ bias,
                                                    const float* __restrict__ bt,
                                                    float* __restrict__ gout,
                                                    int node_base, int prev_base) {
    int bid = blockIdx.x;
    int node = bid / NKC;
    int kc = bid % NKC;
    int k0 = kc * KCH;
    int tid = threadIdx.x;

    const fvec4* Wp = (const fvec4*)W +
                      ((size_t)(node_base + node) * 2048 + (size_t)k0) * 256 + tid;
    // prefetch first window while staging runs
    fvec4 w[4];
#pragma unroll
    for (int i = 0; i < 4; ++i)
        w[i] = __builtin_nontemporal_load(Wp + (size_t)i * 256);

    __shared__ float fs[KCH * 8];
    for (int idx = tid; idx < KCH * 8; idx += 256) {
        int kk = idx % KCH;
        int b = idx / KCH;
        int k = k0 + kk;
        int col = k & 1023;
        float v;
        if (MODE == 0) {
            float p = 0.f;
#pragma unroll
            for (int tc = 0; tc < 8; ++tc)
                p += gprev[(size_t)((b * 8 + node) * 8 + tc) * D + col];
            v = p * (1.0f / 256.0f);
        } else {
            int src = 2 * node + (k >> 10);
            float p = bias[(size_t)(prev_base + src) * D + col];
#pragma unroll 16
            for (int kcp = 0; kcp < KCPREV; ++kcp)
                p += gprev[(size_t)((src * KCPREV + kcp) * 8 + b) * D + col];
            float u = p - bt[(size_t)(prev_base + src) * D + col];
            v = (u > 0.0f) ? p : 0.0f;
        }
        fs[kk * 8 + b] = v;
    }
    __syncthreads();

    fvec4 acc[8];
#pragma unroll
    for (int b = 0; b < 8; ++b) acc[b] = (fvec4){0.f, 0.f, 0.f, 0.f};

#pragma unroll 1
    for (int kk = 0; kk < KCH; kk += 4) {
        fvec4 cur[4];
#pragma unroll
        for (int i = 0; i < 4; ++i) cur[i] = w[i];
        if (kk + 4 < KCH) {
#pragma unroll
            for (int i = 0; i < 4; ++i)
                w[i] = __builtin_nontemporal_load(Wp + (size_t)(kk + 4 + i) * 256);
        }
#pragma unroll
        for (int i = 0; i < 4; ++i) {
#pragma unroll
            for (int b = 0; b < 8; ++b)
                acc[b] += cur[i] * fs[(kk + i) * 8 + b];
        }
    }

    fvec4* op = (fvec4*)gout + (size_t)((node * NKC + kc) * 8) * 256 + tid;
#pragma unroll
    for (int b = 0; b < 8; ++b) op[(size_t)b * 256] = acc[b];
}

// ---------------- root: reduce level-0 partials, bias, gate ---------------
// gpart = [KC kc][8 b][1024 col]; 512 blocks: (b, 16-col group)
template <int KC>
__global__ void __launch_bounds__(256, 2) root_gate(const float* __restrict__ gpart,
                                                    const float* __restrict__ bias,
                                                    const float* __restrict__ bt,
                                                    float* __restrict__ root) {
    int b = blockIdx.x >> 6;
    int colg = blockIdx.x & 63;
    int tid = threadIdx.x;
    int c = tid & 15, s = tid >> 4;
    int col = colg * 16 + c;
    float p = 0.f;
#pragma unroll 4
    for (int kc = s; kc < KC; kc += 16)
        p += gpart[(size_t)(kc * 8 + b) * D + col];
    __shared__ float sm[256];
    sm[s * 16 + c] = p;
    __syncthreads();
    if (tid < 16) {
        int col2 = colg * 16 + tid;
        float tot = bias[col2];
#pragma unroll
        for (int ss = 0; ss < 16; ++ss) tot += sm[ss * 16 + tid];
        float u = tot - bt[col2];
        root[b * D + col2] = (u > 0.0f) ? tot : 0.0f;
    }
}

// ---------------- final: out = layernorm(root[b] + x[row]) ----------------
// 4096 blocks x 8 rows; one wave per row-pair; x cached, out NT-stored.
__global__ void __launch_bounds__(256, 2) add_ln(const float* __restrict__ x,
                                                 const float* __restrict__ root,
                                                 const float* __restrict__ lw,
                                                 const float* __restrict__ lb,
                                                 float* __restrict__ out) {
    int tid = threadIdx.x;
    int wv = tid >> 6, lane = tid & 63;
    int row0 = blockIdx.x * 8 + wv;
    int b = (blockIdx.x * 8) >> 12;
    const fvec4* xp = (const fvec4*)x;
    const fvec4* rp = (const fvec4*)root + b * 256;
    const fvec4* lwp = (const fvec4*)lw;
    const fvec4* lbp = (const fvec4*)lb;

    fvec4 rv[4], lwv[4], lbv[4];
#pragma unroll
    for (int j = 0; j < 4; ++j) {
        rv[j] = rp[j * 64 + lane];
        lwv[j] = lwp[j * 64 + lane];
        lbv[j] = lbp[j * 64 + lane];
    }
#pragma unroll
    for (int r = 0; r < 2; ++r) {
        int row = row0 + r * 4;
        fvec4 v[4];
        float s = 0.f, q = 0.f;
#pragma unroll
        for (int j = 0; j < 4; ++j) {
            fvec4 xv = xp[(size_t)row * 256 + j * 64 + lane];
            v[j] = xv + rv[j];
            s += v[j].x + v[j].y + v[j].z + v[j].w;
            q += v[j].x * v[j].x + v[j].y * v[j].y + v[j].z * v[j].z + v[j].w * v[j].w;
        }
#pragma unroll
        for (int off = 32; off; off >>= 1) {
            s += __shfl_xor(s, off);
            q += __shfl_xor(q, off);
        }
        float mean = s * (1.0f / D);
        float var = q * (1.0f / D) - mean * mean;
        float rstd = rsqrtf(var + 1e-5f);
        fvec4* op = (fvec4*)out + (size_t)row * 256;
#pragma unroll
        for (int j = 0; j < 4; ++j) {
            fvec4 o = (v[j] - mean) * rstd * lwv[j] + lbv[j];
            __builtin_nontemporal_store(o, op + j * 64 + lane);
        }
    }
}

// ===================== launcher =====================

extern "C" void kernel_launch(void* const* d_in, const int* in_sizes, int n_in,
                              void* d_out, int out_size, void* d_ws, size_t ws_size,
                              hipStream_t stream) {
    const float* x    = (const float*)d_in[0];
    const float* W    = (const float*)d_in[1];
    const float* bias = (const float*)d_in[2];
    const float* bt   = (const float*)d_in[3];
    const float* lw   = (const float*)d_in[4];
    const float* lb   = (const float*)d_in[5];
    float* out = (float*)d_out;

    float* ws = (float*)d_ws;
    float* lpart = ws;                    // 8*8*8*1024          = 524288 floats
    float* gA    = lpart + 524288;        // 8n*32kc*8b*1024     = 2097152
    float* gB    = gA + 2097152;          // up to 256kc*8b*1024 = 2097152
    float* root  = gB + 2097152;          // 8*1024

    // 1) leaf partial sums (rows 0..2047 of each batch)
    leaves_partial<<<512, 256, 0, stream>>>(x, lpart);

    // 2) tree levels, gate fused into consumer staging; 256 blocks each
    // leaf level (nodes 7..14): mean(lpart) -> gA  [8 nodes x 32 kc, KCH=64]
    tree_gemm<64, 32, 8, 0><<<256, 256, 0, stream>>>(lpart, W, bias, bt, gA, 7, 0);
    // level 2 (nodes 3..6): gate(gA, base 7) -> gB [4 x 64, KCH=32]
    tree_gemm<32, 64, 32, 1><<<256, 256, 0, stream>>>(gA, W, bias, bt, gB, 3, 7);
    // level 1 (nodes 1..2): gate(gB, base 3) -> gA [2 x 128, KCH=16]
    tree_gemm<16, 128, 64, 1><<<256, 256, 0, stream>>>(gB, W, bias, bt, gA, 1, 3);
    // level 0 (node 0): gate(gA, base 1) -> gB     [1 x 256, KCH=8]
    tree_gemm<8, 256, 128, 1><<<256, 256, 0, stream>>>(gA, W, bias, bt, gB, 0, 1);

    // 3) root = gate(bias0 + sum_kc gB, bt0)
    root_gate<256><<<512, 256, 0, stream>>>(gB, bias, bt, root);

    // 4) out = layernorm(root + x)
    add_ln<<<NB * T / 8, 256, 0, stream>>>(x, root, lw, lb, out);
}